// Round 3
// baseline (1316.454 us; speedup 1.0000x reference)
//
#include <hip/hip_runtime.h>
#include <stdint.h>
#include <stddef.h>

#define N_NODES 24
#define MAX_K   4
#define BATCH   16
#define CIN     64
#define CCH     128
#define HIN     64
#define HH      32
#define PIXELS  (BATCH*HH*HH)          /* 16384 */
#define NODE_ELEMS (BATCH*CCH*HH*HH)   /* 2097152 floats = 8 MB */

/* ---------------- numpy RandomState(42) emulation (host side) ---------------- */
namespace nprng {
struct MT { uint32_t key[624]; int pos; };
static void seed_mt(MT& s, uint32_t sd){
  for(int i=0;i<624;i++){ s.key[i]=sd; sd = 1812433253u*(sd^(sd>>30)) + (uint32_t)i + 1u; }
  s.pos = 624;
}
static void gen(MT& s){
  const uint32_t UP=0x80000000u, LOW=0x7fffffffu, MA=0x9908b0dfu;
  uint32_t y; int i;
  for(i=0;i<227;i++){ y=(s.key[i]&UP)|(s.key[i+1]&LOW); s.key[i]=s.key[i+397]^(y>>1)^((y&1u)?MA:0u); }
  for(;i<623;i++){ y=(s.key[i]&UP)|(s.key[i+1]&LOW); s.key[i]=s.key[i-227]^(y>>1)^((y&1u)?MA:0u); }
  y=(s.key[623]&UP)|(s.key[0]&LOW); s.key[623]=s.key[396]^(y>>1)^((y&1u)?MA:0u);
  s.pos=0;
}
static uint32_t next32(MT& s){
  if(s.pos>=624) gen(s);
  uint32_t y=s.key[s.pos++];
  y^=y>>11; y^=(y<<7)&0x9d2c5680u; y^=(y<<15)&0xefc60000u; y^=y>>18;
  return y;
}
static uint64_t next64(MT& s){ uint64_t hi=next32(s); uint64_t lo=next32(s); return (hi<<32)|lo; }
static uint64_t gen_mask(uint64_t r){ r|=r>>1;r|=r>>2;r|=r>>4;r|=r>>8;r|=r>>16;r|=r>>32; return r; }
/* legacy RandomState.randint: single 32-bit draws when range fits 32 bits */
static long long np_randint(MT& s, long long low, long long high){
  uint64_t rng = (uint64_t)(high - 1 - low);
  if(rng==0) return low;
  uint64_t mask = gen_mask(rng), v;
  if(rng <= 0xffffffffull){ do { v = (uint64_t)next32(s) & mask; } while(v > rng); }
  else                    { do { v = next64(s) & mask; } while(v > rng); }
  return low + (long long)v;
}
static uint64_t np_interval(MT& s, uint64_t mx){
  if(mx==0) return 0;
  uint64_t mask = gen_mask(mx), v;
  if(mx <= 0xffffffffull){ do { v = (uint64_t)next32(s) & mask; } while(v > mx); }
  else                   { do { v = next64(s) & mask; } while(v > mx); }
  return v;
}
} // namespace nprng

/* ---------------- descriptors ---------------- */
struct NodeDesc {
  const float* pred[MAX_K];
  float* outp;
  int k;
  int idx;
};
struct LevelDesc {
  NodeDesc nd[8];     /* max nodes launched per level-kernel call */
};
struct PtrList { const float* p[N_NODES]; int n; };

/* ---------------- fused node kernel (nodes >= 1) ----------------
   block: 512 threads, one 8x8 spatial tile of one image, all 128 channels.
   phase1: gated-agg + relu -> zin[c][10x10] (halo)
   phase2: depthwise 3x3    -> ts[c][64]
   phase3: pointwise 128->128 + BN -> out                                  */
__global__ __launch_bounds__(512)
void k_node(LevelDesc L, const float* __restrict__ aggw, const float* __restrict__ dw,
            const float* __restrict__ pw, const float* __restrict__ gamma,
            const float* __restrict__ beta)
{
  const NodeDesc nd = L.nd[blockIdx.y];
  const int idx = nd.idx, k = nd.k;
  const int tile = blockIdx.x & 15, n = blockIdx.x >> 4;
  const int y0 = (tile >> 2) * 8, x0 = (tile & 3) * 8;
  const int tid = threadIdx.x;

  __shared__ float zin[128][100];   /* 51.2 KB */
  __shared__ float ts[128][64];     /* 32.8 KB */

  const float* agg = aggw + idx * 4;
  float w0 = 1.0f/(1.0f + __expf(-agg[0]));
  float w1 = (k>1) ? 1.0f/(1.0f + __expf(-agg[1])) : 0.0f;
  float w2 = (k>2) ? 1.0f/(1.0f + __expf(-agg[2])) : 0.0f;
  float w3 = (k>3) ? 1.0f/(1.0f + __expf(-agg[3])) : 0.0f;

  /* phase 1: 128 ch x 100 halo pixels */
  for(int i = tid; i < 12800; i += 512){
    int c = i / 100, r = i - c*100;
    int yy = r / 10, xx = r - yy*10;
    int iy = y0 - 1 + yy, ix = x0 - 1 + xx;
    float v = 0.0f;
    if(iy >= 0 && iy < 32 && ix >= 0 && ix < 32){
      size_t off = (((size_t)(n*128 + c)) << 10) + (iy << 5) + ix;
      v = w0 * nd.pred[0][off];
      if(k > 1) v += w1 * nd.pred[1][off];
      if(k > 2) v += w2 * nd.pred[2][off];
      if(k > 3) v += w3 * nd.pred[3][off];
    }
    zin[c][r] = v > 0.0f ? v : 0.0f;
  }
  __syncthreads();

  /* phase 2: depthwise 3x3 stride 1 */
  const int px = tid & 63, wy = px >> 3, wx = px & 7;
  const int cbase = (tid >> 6) * 16;
  const float* dwn = dw + (size_t)(idx - 1) * 9 * 128;
  for(int cc = 0; cc < 16; ++cc){
    int c = cbase + cc;
    float acc = 0.0f;
#pragma unroll
    for(int ky = 0; ky < 3; ++ky)
#pragma unroll
      for(int kx = 0; kx < 3; ++kx)
        acc += dwn[(ky*3+kx)*128 + c] * zin[c][(wy+ky)*10 + wx + kx];
    ts[c][px] = acc;
  }
  __syncthreads();

  /* phase 3: pointwise 128->128 + BN */
  const float* W = pw + (size_t)(idx - 1) * 128 * 128;
  const int cog = tid >> 6;           /* 8 groups x 16 cout */
  float acc[16];
#pragma unroll
  for(int j = 0; j < 16; ++j) acc[j] = 0.0f;
  for(int ci = 0; ci < 128; ++ci){
    float tv = ts[ci][px];
    const float4* w4 = (const float4*)(W + ci*128 + cog*16);
    float4 a = w4[0], b = w4[1], c2 = w4[2], d = w4[3];
    acc[0]+=tv*a.x;  acc[1]+=tv*a.y;  acc[2]+=tv*a.z;  acc[3]+=tv*a.w;
    acc[4]+=tv*b.x;  acc[5]+=tv*b.y;  acc[6]+=tv*b.z;  acc[7]+=tv*b.w;
    acc[8]+=tv*c2.x; acc[9]+=tv*c2.y; acc[10]+=tv*c2.z;acc[11]+=tv*c2.w;
    acc[12]+=tv*d.x; acc[13]+=tv*d.y; acc[14]+=tv*d.z; acc[15]+=tv*d.w;
  }
  const float* gm = gamma + idx*128;
  const float* bt = beta  + idx*128;
  float* op = nd.outp + (((size_t)n*128) << 10) + ((y0+wy) << 5) + (x0+wx);
#pragma unroll
  for(int j = 0; j < 16; ++j){
    int co = cog*16 + j;
    op[(size_t)co << 10] = acc[j]*gm[co] + bt[co];
  }
}

/* ---------------- fused node-0 kernel (stride-2, CIN=64) ---------------- */
__global__ __launch_bounds__(512)
void k_node0(const float* __restrict__ x, const float* __restrict__ aggw,
             const float* __restrict__ dw0, const float* __restrict__ pw0,
             const float* __restrict__ gamma, const float* __restrict__ beta,
             float* __restrict__ outp)
{
  const int tile = blockIdx.x & 15, n = blockIdx.x >> 4;
  const int y0 = (tile >> 2) * 8, x0 = (tile & 3) * 8;
  const int tid = threadIdx.x;

  __shared__ float zin[64][289];    /* 74 KB: 17x17 halo per channel */
  __shared__ float ts[64][64];      /* 16 KB */

  float g = 1.0f/(1.0f + __expf(-aggw[0]));

  /* phase 1: SAME stride-2: pad_lo=0, pad_hi=1; iy = 2*y0 + yy, yy 0..16 */
  for(int i = tid; i < 64*289; i += 512){
    int c = i / 289, r = i - c*289;
    int yy = r / 17, xx = r - yy*17;
    int iy = 2*y0 + yy, ix = 2*x0 + xx;
    float v = 0.0f;
    if(iy < 64 && ix < 64){
      size_t off = (((size_t)(n*64 + c)) << 12) + (iy << 6) + ix;
      v = g * x[off];
    }
    zin[c][r] = v > 0.0f ? v : 0.0f;
  }
  __syncthreads();

  /* phase 2: depthwise 3x3 stride 2 */
  const int px = tid & 63, wy = px >> 3, wx = px & 7;
  const int cbase = (tid >> 6) * 8;
  for(int cc = 0; cc < 8; ++cc){
    int c = cbase + cc;
    float acc = 0.0f;
#pragma unroll
    for(int ky = 0; ky < 3; ++ky)
#pragma unroll
      for(int kx = 0; kx < 3; ++kx)
        acc += dw0[(ky*3+kx)*64 + c] * zin[c][(2*wy+ky)*17 + 2*wx + kx];
    ts[c][px] = acc;
  }
  __syncthreads();

  /* phase 3: pointwise 64->128 + BN */
  const int cog = tid >> 6;
  float acc[16];
#pragma unroll
  for(int j = 0; j < 16; ++j) acc[j] = 0.0f;
  for(int ci = 0; ci < 64; ++ci){
    float tv = ts[ci][px];
    const float4* w4 = (const float4*)(pw0 + ci*128 + cog*16);
    float4 a = w4[0], b = w4[1], c2 = w4[2], d = w4[3];
    acc[0]+=tv*a.x;  acc[1]+=tv*a.y;  acc[2]+=tv*a.z;  acc[3]+=tv*a.w;
    acc[4]+=tv*b.x;  acc[5]+=tv*b.y;  acc[6]+=tv*b.z;  acc[7]+=tv*b.w;
    acc[8]+=tv*c2.x; acc[9]+=tv*c2.y; acc[10]+=tv*c2.z;acc[11]+=tv*c2.w;
    acc[12]+=tv*d.x; acc[13]+=tv*d.y; acc[14]+=tv*d.z; acc[15]+=tv*d.w;
  }
  float* op = outp + (((size_t)n*128) << 10) + ((y0+wy) << 5) + (x0+wx);
#pragma unroll
  for(int j = 0; j < 16; ++j){
    int co = cog*16 + j;
    op[(size_t)co << 10] = acc[j]*gamma[co] + beta[co];
  }
}

/* ---------------- final mean over sinks (vectorized) ---------------- */
__global__ __launch_bounds__(256)
void k_mean4(PtrList pl, float scale, float4* __restrict__ out, int n4)
{
  int i = blockIdx.x*256 + threadIdx.x;
  if(i >= n4) return;
  float4 s = make_float4(0.f,0.f,0.f,0.f);
  for(int j = 0; j < pl.n; ++j){
    float4 v = ((const float4*)pl.p[j])[i];
    s.x += v.x; s.y += v.y; s.z += v.z; s.w += v.w;
  }
  s.x *= scale; s.y *= scale; s.z *= scale; s.w *= scale;
  out[i] = s;
}

/* ---------------- host ---------------- */
extern "C" void kernel_launch(void* const* d_in, const int* in_sizes, int n_in,
                              void* d_out, int out_size, void* d_ws, size_t ws_size,
                              hipStream_t stream)
{
  const float* x     = (const float*)d_in[0];
  const float* aggw  = (const float*)d_in[1];
  const float* dw0   = (const float*)d_in[2];
  const float* pw0   = (const float*)d_in[3];
  const float* dw    = (const float*)d_in[4];
  const float* pw    = (const float*)d_in[5];
  const float* gamma = (const float*)d_in[6];
  const float* beta  = (const float*)d_in[7];
  float* out = (float*)d_out;

  /* rebuild the reference's static DAG: np.random.RandomState(42) */
  int preds[N_NODES][MAX_K]; int npred[N_NODES];
  {
    nprng::MT st; nprng::seed_mt(st, 42u);
    npred[0] = 0;
    for(int i = 1; i < N_NODES; ++i){
      int mx = (i < MAX_K) ? i : MAX_K;
      int k = (int)nprng::np_randint(st, 1, (long long)mx + 1);
      int perm[N_NODES];
      for(int q = 0; q < i; ++q) perm[q] = q;
      for(int q = i-1; q >= 1; --q){
        int j = (int)nprng::np_interval(st, (uint64_t)q);
        int tt = perm[q]; perm[q] = perm[j]; perm[j] = tt;
      }
      int tmp[MAX_K];
      for(int a = 0; a < k; ++a) tmp[a] = perm[a];
      for(int a = 1; a < k; ++a){ int v = tmp[a]; int b = a-1;
        while(b >= 0 && tmp[b] > v){ tmp[b+1] = tmp[b]; --b; } tmp[b+1] = v; }
      npred[i] = k;
      for(int a = 0; a < k; ++a) preds[i][a] = tmp[a];
    }
  }

  /* sinks + topological levels */
  int uses[N_NODES]; bool sink[N_NODES];
  for(int i = 0; i < N_NODES; ++i) uses[i] = 0;
  for(int i = 0; i < N_NODES; ++i) for(int q = 0; q < npred[i]; ++q) uses[preds[i][q]]++;
  int nsinks = 0;
  for(int i = 0; i < N_NODES; ++i){ sink[i] = (uses[i] == 0); if(sink[i]) nsinks++; }

  int level[N_NODES]; int maxlev = 0;
  level[0] = 0;
  for(int i = 1; i < N_NODES; ++i){
    int L = 0;
    for(int q = 0; q < npred[i]; ++q){ int l = level[preds[i][q]] + 1; if(l > L) L = l; }
    level[i] = L; if(L > maxlev) maxlev = L;
  }

  /* liveness slot allocation, in LEVEL execution order, frees deferred to
     level boundaries (same-level nodes run concurrently) */
  int rem[N_NODES];
  for(int i = 0; i < N_NODES; ++i) rem[i] = uses[i] + (sink[i] ? 1 : 0);
  int slot_of[N_NODES]; bool slot_used[N_NODES]; int nslots = 0;
  for(int i = 0; i < N_NODES; ++i) slot_used[i] = false;
  for(int L = 0; L <= maxlev; ++L){
    /* allocate for this level */
    for(int i = 0; i < N_NODES; ++i){
      if(level[i] != L) continue;
      int s = -1;
      for(int q = 0; q < nslots; ++q) if(!slot_used[q]){ s = q; break; }
      if(s < 0) s = nslots++;
      slot_used[s] = true; slot_of[i] = s;
    }
    /* then release preds fully consumed by this level */
    for(int i = 0; i < N_NODES; ++i){
      if(level[i] != L) continue;
      for(int q = 0; q < npred[i]; ++q){
        int p = preds[i][q];
        if(--rem[p] == 0) slot_used[slot_of[p]] = false;
      }
    }
  }

  float* slotbase = (float*)d_ws;
  if(ws_size < (size_t)nslots * NODE_ELEMS * sizeof(float)) return;

  /* level 0: node 0 */
  k_node0<<<dim3(256), dim3(512), 0, stream>>>(x, aggw, dw0, pw0, gamma, beta,
        slotbase + (size_t)slot_of[0]*NODE_ELEMS);

  /* levels 1..maxlev: batch nodes per level (chunks of 8) */
  for(int L = 1; L <= maxlev; ++L){
    int ids[N_NODES]; int cnt = 0;
    for(int i = 0; i < N_NODES; ++i) if(level[i] == L) ids[cnt++] = i;
    for(int off = 0; off < cnt; off += 8){
      int m = (cnt - off < 8) ? (cnt - off) : 8;
      LevelDesc ld;
      for(int j = 0; j < m; ++j){
        int i = ids[off + j];
        NodeDesc& nd = ld.nd[j];
        nd.k = npred[i]; nd.idx = i;
        nd.outp = slotbase + (size_t)slot_of[i]*NODE_ELEMS;
        for(int q = 0; q < MAX_K; ++q){
          int src = preds[i][(q < npred[i]) ? q : 0];
          nd.pred[q] = slotbase + (size_t)slot_of[src]*NODE_ELEMS;
        }
      }
      k_node<<<dim3(256, m), dim3(512), 0, stream>>>(ld, aggw, dw, pw, gamma, beta);
    }
  }

  /* final mean over sinks */
  PtrList pl; pl.n = 0;
  for(int i = 0; i < N_NODES; ++i) if(sink[i]) pl.p[pl.n++] = slotbase + (size_t)slot_of[i]*NODE_ELEMS;
  k_mean4<<<dim3(NODE_ELEMS/4/256), dim3(256), 0, stream>>>(pl, 1.0f/(float)pl.n,
        (float4*)out, NODE_ELEMS/4);
}